// Round 7
// baseline (124.873 us; speedup 1.0000x reference)
//
#include <hip/hip_runtime.h>

#define NFEAT 512
#define NCLS 8
#define NHID 128
#define NPB 16        // nodes per bin (N=50000 -> 3125 exact bins)
#define NBIN 3125
#define NBIN16 3136   // padded to multiple of 16
#define NBG 196       // NBIN16/16 bin-groups
#define WINE 2048     // edges per window

typedef float4 f4;
typedef unsigned int u32;

// W12 = W_conv @ W_fc [512][8]; bias2 = b_conv @ W_fc + b_fc
__global__ __launch_bounds__(256) void init_kernel(
    const float* __restrict__ W1, const float* __restrict__ W2,
    const float* __restrict__ b1, const float* __restrict__ b2,
    float* __restrict__ W12, float* __restrict__ bias2)
{
    int t = blockIdx.x * 256 + threadIdx.x;
    if (t < NFEAT * NCLS) {
        int k = t >> 3, c = t & 7;
        const float* w1r = W1 + k * NHID;
        float acc = 0.f;
        #pragma unroll 8
        for (int j = 0; j < NHID; ++j) acc = fmaf(w1r[j], W2[j * NCLS + c], acc);
        W12[t] = acc;
    }
    if (t < NCLS) {
        float acc = b2[t];
        for (int j = 0; j < NHID; ++j) acc = fmaf(b1[j], W2[j * NCLS + t], acc);
        bias2[t] = acc;
    }
}

// Fused: gemm g = x @ W12 (unscaled, wave/row) + per-window bin histogram.
// Every 8th block additionally histograms its 2048-edge window into LDS and
// writes wincnt[bingroup][win][16] as full coalesced lines. No global atomics.
__global__ __launch_bounds__(256) void fusedA_kernel(
    const int* __restrict__ dst, const float* __restrict__ x,
    const float* __restrict__ W12, int* __restrict__ wincnt,
    float* __restrict__ g, int N, int E, int NW)
{
    const int tid = threadIdx.x;
    const int lane = tid & 63;
    const int bid = blockIdx.x;

    if ((bid & 7) == 0) {   // window duty
        int win = bid >> 3;
        __shared__ int hist[NBIN16];
        for (int k = tid; k < NBIN16; k += 256) hist[k] = 0;
        __syncthreads();
        int e0 = win * WINE;
        #pragma unroll
        for (int j = 0; j < 8; ++j) {
            int e = e0 + tid + j * 256;
            if (e < E) atomicAdd(&hist[dst[e] >> 4], 1);
        }
        __syncthreads();
        if (tid < NBG) {
            int4* dst4 = (int4*)(wincnt + (size_t)tid * NW * 16 + (size_t)win * 16);
            const int4* src4 = (const int4*)(hist + tid * 16);
            dst4[0] = src4[0]; dst4[1] = src4[1]; dst4[2] = src4[2]; dst4[3] = src4[3];
        }
    }

    // gemm phase
    float w[2][4][8];
    #pragma unroll
    for (int j = 0; j < 2; ++j)
        #pragma unroll
        for (int m = 0; m < 4; ++m) {
            const f4* wp = (const f4*)(W12 + (j * 256 + lane * 4 + m) * 8);
            f4 lo = wp[0], hi = wp[1];
            w[j][m][0] = lo.x; w[j][m][1] = lo.y; w[j][m][2] = lo.z; w[j][m][3] = lo.w;
            w[j][m][4] = hi.x; w[j][m][5] = hi.y; w[j][m][6] = hi.z; w[j][m][7] = hi.w;
        }
    int wave = bid * 4 + (tid >> 6);
    int nwaves = gridDim.x * 4;
    for (int row = wave; row < N; row += nwaves) {
        const f4* xr = (const f4*)(x + (size_t)row * NFEAT);
        f4 a0 = xr[lane];
        f4 a1 = xr[lane + 64];
        float acc[8];
        #pragma unroll
        for (int c = 0; c < 8; ++c) {
            acc[c] = a0.x * w[0][0][c] + a0.y * w[0][1][c]
                   + a0.z * w[0][2][c] + a0.w * w[0][3][c]
                   + a1.x * w[1][0][c] + a1.y * w[1][1][c]
                   + a1.z * w[1][2][c] + a1.w * w[1][3][c];
        }
        #pragma unroll
        for (int d = 32; d >= 1; d >>= 1)
            #pragma unroll
            for (int c = 0; c < 8; ++c)
                acc[c] += __shfl_xor(acc[c], d);
        if (lane == 0) {
            f4* go = (f4*)(g + (size_t)row * 8);
            go[0] = make_float4(acc[0], acc[1], acc[2], acc[3]);
            go[1] = make_float4(acc[4], acc[5], acc[6], acc[7]);
        }
    }
}

// Per-bin exclusive prefix over windows (in place) + per-bin totals.
// Block = 16 bins; thread (bl=t&15, chunk=t>>4) owns up to 24 windows.
__global__ __launch_bounds__(256) void colprefix_kernel(
    int* __restrict__ wincnt, int* __restrict__ colsum, int NW)
{
    const int gso = blockIdx.x;
    const int t = threadIdx.x;
    const int bl = t & 15, chunk = t >> 4;
    const int CPW = (NW + 15) / 16;   // 20 for NW=313 (<=24)
    int vals[24];
    int s = 0;
    for (int k = 0; k < CPW; ++k) {
        int win = chunk * CPW + k;
        int v = 0;
        if (win < NW) v = wincnt[(size_t)gso * NW * 16 + (size_t)win * 16 + bl];
        vals[k] = v; s += v;
    }
    __shared__ int part[256];
    part[bl * 16 + chunk] = s;
    __syncthreads();
    int base = 0;
    for (int c = 0; c < chunk; ++c) base += part[bl * 16 + c];
    int run = base;
    for (int k = 0; k < CPW; ++k) {
        int win = chunk * CPW + k;
        if (win < NW) {
            wincnt[(size_t)gso * NW * 16 + (size_t)win * 16 + bl] = run;
            run += vals[k];
        }
    }
    if (chunk == 15) colsum[gso * 16 + bl] = run;
}

// Exclusive scan of 3136 bin totals (single block).
__global__ __launch_bounds__(256) void colscan_kernel(
    const int* __restrict__ colsum, int* __restrict__ colscan)
{
    const int t = threadIdx.x;
    const int CE = (NBIN16 + 255) / 256;  // 13
    int vals[13];
    int s = 0;
    for (int j = 0; j < CE; ++j) {
        int idx = t * CE + j;
        int v = (idx < NBIN16) ? colsum[idx] : 0;
        vals[j] = v; s += v;
    }
    __shared__ int part[256];
    part[t] = s;
    __syncthreads();
    #pragma unroll
    for (int d = 1; d < 256; d <<= 1) {
        int u = (t >= d) ? part[t - d] : 0;
        __syncthreads();
        part[t] += u;
        __syncthreads();
    }
    int base = (t == 0) ? 0 : part[t - 1];
    for (int j = 0; j < CE; ++j) {
        int idx = t * CE + j;
        if (idx < NBIN16) { colscan[idx] = base; base += vals[j]; }
    }
    if (t == 255) colscan[NBIN16] = part[255];
}

// Place edges: rank within (win,bin) via LDS returning atomic; slot exact.
// ebuf[slot] = src | (dst&15)<<16. Fire-and-forget stores only.
__global__ __launch_bounds__(256) void pass2_kernel(
    const int* __restrict__ src, const int* __restrict__ dst,
    const int* __restrict__ wincnt, const int* __restrict__ colscan,
    u32* __restrict__ ebuf, int E, int NW)
{
    const int win = blockIdx.x;
    const int tid = threadIdx.x;
    __shared__ int loff[NBIN16];
    __shared__ int rank[NBIN16];
    for (int k = tid; k < NBIN16; k += 256) {
        loff[k] = colscan[k] + wincnt[(size_t)(k >> 4) * NW * 16 + (size_t)win * 16 + (k & 15)];
        rank[k] = 0;
    }
    __syncthreads();
    int e0 = win * WINE;
    #pragma unroll
    for (int j = 0; j < 8; ++j) {
        int e = e0 + tid + j * 256;
        if (e < E) {
            int d = dst[e];
            int b = d >> 4;
            int r = atomicAdd(&rank[b], 1);
            ebuf[loff[b] + r] = (u32)src[e] | ((u32)(d & 15) << 16);
        }
    }
}

// Wave per bin: count per-node in-degree from CSR, write deg, scale g by dinv in place.
__global__ __launch_bounds__(256) void degscale_kernel(
    const u32* __restrict__ ebuf, const int* __restrict__ colscan,
    float* __restrict__ g, int* __restrict__ deg)
{
    const int tid = threadIdx.x;
    const int wv = tid >> 6, lane = tid & 63;
    const int bin = blockIdx.x * 4 + wv;
    if (bin >= NBIN) return;
    __shared__ int cnt_s[4][NPB];
    if (lane < NPB) cnt_s[wv][lane] = 0;
    int s0 = colscan[bin], s1 = colscan[bin + 1];
    for (int k = s0 + lane; k < s1; k += 64) {
        u32 u = ebuf[k];
        atomicAdd(&cnt_s[wv][u >> 16], 1);
    }
    #pragma unroll
    for (int half = 0; half < 2; ++half) {
        int k2 = lane + half * 64;
        int node = k2 >> 3, c = k2 & 7;
        int i = bin * NPB + node;
        float di = rsqrtf((float)cnt_s[wv][node] + 1.0f);
        g[(size_t)i * 8 + c] *= di;
    }
    if (lane < NPB) deg[bin * NPB + lane] = cnt_s[wv][lane];
}

// Wave per bin: LDS-accumulate scaled g over in-edges, add self, scale, bias, write out.
__global__ __launch_bounds__(256) void gather_kernel(
    const u32* __restrict__ ebuf, const int* __restrict__ colscan,
    const float* __restrict__ g, const int* __restrict__ deg,
    const float* __restrict__ bias2, float* __restrict__ out)
{
    const int tid = threadIdx.x;
    const int wv = tid >> 6, lane = tid & 63;
    const int bin = blockIdx.x * 4 + wv;
    if (bin >= NBIN) return;
    __shared__ float acc_s[4][NPB * 8];
    acc_s[wv][lane] = 0.f;
    acc_s[wv][lane + 64] = 0.f;
    int s0 = colscan[bin], s1 = colscan[bin + 1];
    for (int k = s0 + lane; k < s1; k += 64) {
        u32 u = ebuf[k];
        int s = u & 0xFFFF;
        int dl = u >> 16;
        const f4* gs = (const f4*)(g + (size_t)s * 8);
        f4 a = gs[0], b = gs[1];
        float* A = &acc_s[wv][dl * 8];
        atomicAdd(A + 0, a.x); atomicAdd(A + 1, a.y);
        atomicAdd(A + 2, a.z); atomicAdd(A + 3, a.w);
        atomicAdd(A + 4, b.x); atomicAdd(A + 5, b.y);
        atomicAdd(A + 6, b.z); atomicAdd(A + 7, b.w);
    }
    #pragma unroll
    for (int half = 0; half < 2; ++half) {
        int k2 = lane + half * 64;
        int node = k2 >> 3, c = k2 & 7;
        int i = bin * NPB + node;
        float di = rsqrtf((float)deg[i] + 1.0f);
        out[(size_t)i * 8 + c] = fmaf(di, acc_s[wv][k2] + g[(size_t)i * 8 + c], bias2[c]);
    }
}

extern "C" void kernel_launch(void* const* d_in, const int* in_sizes, int n_in,
                              void* d_out, int out_size, void* d_ws, size_t ws_size,
                              hipStream_t stream)
{
    const float* x  = (const float*)d_in[0];
    const int*   ei = (const int*)d_in[1];
    const float* W1 = (const float*)d_in[2];
    const float* b1 = (const float*)d_in[3];
    const float* W2 = (const float*)d_in[4];
    const float* b2 = (const float*)d_in[5];
    float* out = (float*)d_out;

    const int N = in_sizes[0] / NFEAT;   // 50000
    const int E = in_sizes[1] / 2;       // 640000
    const int* src = ei;
    const int* dst = ei + E;

    const int NW = (E + WINE - 1) / WINE;  // 313
    const int FB = NW * 8;                 // 2504

    char* ws = (char*)d_ws;
    size_t off = 0;
    auto alloc = [&](size_t bytes) {
        char* p = ws + off;
        off += (bytes + 255) & ~(size_t)255;
        return p;
    };
    int*   wincnt  = (int*)alloc((size_t)NBG * NW * 16 * 4);   // ~3.93 MB
    int*   colsum  = (int*)alloc((size_t)NBIN16 * 4);
    int*   colscan = (int*)alloc(((size_t)NBIN16 + 1) * 4);
    u32*   ebuf    = (u32*)alloc((size_t)E * 4);               // 2.56 MB
    float* g       = (float*)alloc((size_t)N * 8 * 4);         // 1.6 MB
    int*   deg     = (int*)alloc((size_t)N * 4);
    float* W12     = (float*)alloc(NFEAT * NCLS * 4);
    float* bias2   = (float*)alloc(NCLS * 4);

    init_kernel<<<(NFEAT * NCLS + 255) / 256, 256, 0, stream>>>(W1, W2, b1, b2, W12, bias2);

    fusedA_kernel<<<FB, 256, 0, stream>>>(dst, x, W12, wincnt, g, N, E, NW);

    colprefix_kernel<<<NBG, 256, 0, stream>>>(wincnt, colsum, NW);

    colscan_kernel<<<1, 256, 0, stream>>>(colsum, colscan);

    pass2_kernel<<<NW, 256, 0, stream>>>(src, dst, wincnt, colscan, ebuf, E, NW);

    const int BB = (NBIN + 3) / 4;   // 782 blocks, wave per bin
    degscale_kernel<<<BB, 256, 0, stream>>>(ebuf, colscan, g, deg);

    gather_kernel<<<BB, 256, 0, stream>>>(ebuf, colscan, g, deg, bias2, out);
}